// Round 4
// baseline (208.944 us; speedup 1.0000x reference)
//
#include <hip/hip_runtime.h>

#define POOLP 7
#define NB 8
#define IH 64
#define IW 64
#define NC 1024
#define NR 32

typedef float vfloat4 __attribute__((ext_vector_type(4)));

// One block per (r, b, py); 256 threads each own one float4 of the 1024
// channels and loop over the 7 px positions.
//
// XCD swizzle: workgroup->XCD assignment is round-robin (blockIdx % 8).
// We map b = blockIdx % 8 so that ALL blocks reading batch image b land on
// the same XCD. Without this, blocks sharing the same image rows spread
// across all 8 XCDs and each per-XCD L2 fetches its own copy of the shared
// rows (~8x L2-fill amplification served by L3). With it, each XCD touches
// only its own ~17 MB image -> fetch-once into that XCD's L2/L3 path.
__global__ __launch_bounds__(256) void roi_align_kernel(
    const float* __restrict__ img,
    const int* __restrict__ rois,
    float* __restrict__ out)
{
    int b = blockIdx.x & 7;          // batch -> XCD (round-robin matches % 8)
    int rest = blockIdx.x >> 3;      // 0..223
    int py = rest % POOLP;
    int r  = rest / POOLP;           // 0..31

    int rx = rois[r * 4 + 0];
    int ry = rois[r * 4 + 1];
    int rw = rois[r * 4 + 2];
    int rh = rois[r * 4 + 3];

    // Replicate reference fp32 arithmetic exactly:
    // coord = (out + 0.5) * (size / 7) - 0.5
    float sx = (float)rw / (float)POOLP;
    float sy = (float)rh / (float)POOLP;

    float cy = ((float)py + 0.5f) * sy - 0.5f;
    float fy = floorf(cy);
    int y0 = max((int)fy, 0);
    int y1 = min(max((int)ceilf(cy), 0), rh - 1);
    float wy = cy - fy;
    int Y0 = ry + y0, Y1 = ry + y1;

    const float* row0 = img + (((size_t)b * IH + Y0) * IW) * NC;
    const float* row1 = img + (((size_t)b * IH + Y1) * IW) * NC;

    int c4 = threadIdx.x;  // float4 index within channels, 0..255

    // Output base for (r, b, py): (((r*NB + b)*POOLP + py)*POOLP + px)*NC + c
    float* obase = out + ((((size_t)r * NB + b) * POOLP + py) * POOLP) * NC;

#pragma unroll
    for (int px = 0; px < POOLP; ++px) {
        float cx = ((float)px + 0.5f) * sx - 0.5f;
        float fx = floorf(cx);
        int x0 = max((int)fx, 0);
        int x1 = min(max((int)ceilf(cx), 0), rw - 1);
        float wx = cx - fx;
        int X0 = rx + x0, X1 = rx + x1;

        const vfloat4* i00 = (const vfloat4*)(row0 + (size_t)X0 * NC);
        const vfloat4* i01 = (const vfloat4*)(row0 + (size_t)X1 * NC);
        const vfloat4* i10 = (const vfloat4*)(row1 + (size_t)X0 * NC);
        const vfloat4* i11 = (const vfloat4*)(row1 + (size_t)X1 * NC);

        vfloat4 v00 = i00[c4];
        vfloat4 v01 = i01[c4];
        vfloat4 v10 = i10[c4];
        vfloat4 v11 = i11[c4];

        vfloat4 top = v00 + (v01 - v00) * wx;
        vfloat4 bot = v10 + (v11 - v10) * wx;
        vfloat4 res = top + (bot - top) * wy;

        __builtin_nontemporal_store(res, (vfloat4*)(obase + (size_t)px * NC) + c4);
    }
}

extern "C" void kernel_launch(void* const* d_in, const int* in_sizes, int n_in,
                              void* d_out, int out_size, void* d_ws, size_t ws_size,
                              hipStream_t stream) {
    const float* img = (const float*)d_in[0];
    const int* rois = (const int*)d_in[1];
    float* out = (float*)d_out;

    int nblocks = NR * NB * POOLP;  // 1792 blocks, each does 7 px positions
    roi_align_kernel<<<nblocks, 256, 0, stream>>>(img, rois, out);
}

// Round 6
// 200.479 us; speedup vs baseline: 1.0422x; 1.0422x over previous
//
#include <hip/hip_runtime.h>

#define POOLP 7
#define NB 8
#define IH 64
#define IW 64
#define NC 1024
#define NR 32

typedef float vfloat4 __attribute__((ext_vector_type(4)));

// One block per (r, b, py); 256 threads each own one float4 of the 1024
// channels and loop over the 7 px positions.
//
// All image reads are nontemporal: the 134 MB image streams through 4 MiB
// per-XCD L2s with ~no reuse value, so default allocating loads just thrash.
// Stores are nontemporal too (51 MB pure stream-out).
__global__ __launch_bounds__(256) void roi_align_kernel(
    const float* __restrict__ img,
    const int* __restrict__ rois,
    float* __restrict__ out)
{
    int b = blockIdx.x & 7;          // batch -> XCD (round-robin matches % 8)
    int rest = blockIdx.x >> 3;      // 0..223
    int py = rest % POOLP;
    int r  = rest / POOLP;           // 0..31

    int rx = rois[r * 4 + 0];
    int ry = rois[r * 4 + 1];
    int rw = rois[r * 4 + 2];
    int rh = rois[r * 4 + 3];

    // Replicate reference fp32 arithmetic exactly:
    // coord = (out + 0.5) * (size / 7) - 0.5
    float sx = (float)rw / (float)POOLP;
    float sy = (float)rh / (float)POOLP;

    float cy = ((float)py + 0.5f) * sy - 0.5f;
    float fy = floorf(cy);
    int y0 = max((int)fy, 0);
    int y1 = min(max((int)ceilf(cy), 0), rh - 1);
    float wy = cy - fy;
    int Y0 = ry + y0, Y1 = ry + y1;

    const float* row0 = img + (((size_t)b * IH + Y0) * IW) * NC;
    const float* row1 = img + (((size_t)b * IH + Y1) * IW) * NC;

    int c4 = threadIdx.x;  // float4 index within channels, 0..255

    // Output base for (r, b, py): (((r*NB + b)*POOLP + py)*POOLP + px)*NC + c
    float* obase = out + ((((size_t)r * NB + b) * POOLP + py) * POOLP) * NC;

#pragma unroll
    for (int px = 0; px < POOLP; ++px) {
        float cx = ((float)px + 0.5f) * sx - 0.5f;
        float fx = floorf(cx);
        int x0 = max((int)fx, 0);
        int x1 = min(max((int)ceilf(cx), 0), rw - 1);
        float wx = cx - fx;
        int X0 = rx + x0, X1 = rx + x1;

        const vfloat4* i00 = (const vfloat4*)(row0 + (size_t)X0 * NC) + c4;
        const vfloat4* i01 = (const vfloat4*)(row0 + (size_t)X1 * NC) + c4;
        const vfloat4* i10 = (const vfloat4*)(row1 + (size_t)X0 * NC) + c4;
        const vfloat4* i11 = (const vfloat4*)(row1 + (size_t)X1 * NC) + c4;

        vfloat4 v00 = __builtin_nontemporal_load(i00);
        vfloat4 v01 = __builtin_nontemporal_load(i01);
        vfloat4 v10 = __builtin_nontemporal_load(i10);
        vfloat4 v11 = __builtin_nontemporal_load(i11);

        vfloat4 top = v00 + (v01 - v00) * wx;
        vfloat4 bot = v10 + (v11 - v10) * wx;
        vfloat4 res = top + (bot - top) * wy;

        __builtin_nontemporal_store(res, (vfloat4*)(obase + (size_t)px * NC) + c4);
    }
}

extern "C" void kernel_launch(void* const* d_in, const int* in_sizes, int n_in,
                              void* d_out, int out_size, void* d_ws, size_t ws_size,
                              hipStream_t stream) {
    const float* img = (const float*)d_in[0];
    const int* rois = (const int*)d_in[1];
    float* out = (float*)d_out;

    int nblocks = NR * NB * POOLP;  // 1792 blocks, each does 7 px positions
    roi_align_kernel<<<nblocks, 256, 0, stream>>>(img, rois, out);
}